// Round 17
// baseline (180.057 us; speedup 1.0000x reference)
//
#include <hip/hip_runtime.h>

// Problem constants
#define BB 16
#define TT 64
#define HH 256
#define NSUB 16              // blocks per batch; block owns a 16-COLUMN slice
#define NBLK (BB * NSUB)     // 256 blocks
#define NTH 320              // waves 0-3 compute (r11 structure), wave 4 = DMA

// d_out layout (floats): hid[B][T][H], out[B][T][2], h_fin[B][H], new_j[B][H][H]
#define OUT_OFF  (BB * TT * HH)            // 262144
#define HFIN_OFF (OUT_OFF + BB * TT * 2)   // 264192
#define NJ_OFF   (HFIN_OFF + BB * HH)      // 268288

// beta * SIGMA_SYN * sqrt(beta) = 0.1 * 0.002 * sqrt(0.1)
#define C_SN    6.324555320336759e-05f
// PERT_SIGMA * sqrt(ALPHA) = 0.1 * 0.5
#define C_NOISE 0.05f

#define SNP 20               // padded sn row: 20 floats = 80B (16B-aligned)

typedef unsigned long long u64;
typedef unsigned int u32;

// Agent-scope RMWs ONLY (proven r4-r16): exchange publishes at the device
// coherence point, fetch_add(0) reads fresh, tag travels with the data.
// r17 theory: step(r11) = local 0.4 + RT 0.9 + SN-STREAM DRAIN 0.8 (vmcnt
// retires in order; the poll's result-read drains the block's 16KB/step sn
// stream EVERY step). Fix = wave specialization: a dedicated DMA wave owns
// the sn stream (vmcnt is per-wave), compute waves poll with a clean counter.
__device__ __forceinline__ void slot_put(u64* p, u64 v) {
    (void)__hip_atomic_exchange(p, v, __ATOMIC_RELAXED, __HIP_MEMORY_SCOPE_AGENT);
}
__device__ __forceinline__ u64 slot_get(u64* p) {
    return __hip_atomic_fetch_add(p, 0ull, __ATOMIC_RELAXED, __HIP_MEMORY_SCOPE_AGENT);
}
__device__ __forceinline__ u64 pack(u32 tag, float v) {
    return ((u64)tag << 32) | (u64)__float_as_uint(v);
}

// LDS-only barrier (r14, proven-safe): drains lgkmcnt but NOT vmcnt -> the
// DMA wave's global loads stay in flight across it; compute waves' LDS
// traffic is ordered. sched_barrier fences pin placement (rule #18).
#define LGKM_BAR() do {                                          \
    asm volatile("s_waitcnt lgkmcnt(0)" ::: "memory");           \
    __builtin_amdgcn_sched_barrier(0);                           \
    __builtin_amdgcn_s_barrier();                                \
    __builtin_amdgcn_sched_barrier(0);                           \
} while (0)

__global__ __launch_bounds__(NTH) void rnn_all(
    const float* __restrict__ x,      // [B,T,2]
    const float* __restrict__ h0,     // [B,H]
    const float* __restrict__ w_in,   // [H,2]
    const float* __restrict__ w_hh,   // [H,H]
    const float* __restrict__ b_hh,   // [H]
    const float* __restrict__ w_out,  // [2,H]
    const float* __restrict__ nper,   // [B,H]
    const float* __restrict__ sn,     // [T,B,H,H]
    const int*   __restrict__ pt_ptr, // scalar
    float*       __restrict__ dout,
    u64*         __restrict__ ws)     // d_ws: [BB][2][NSUB][16] u64 slots
{
    const int tid = threadIdx.x;
    const int bid = blockIdx.x;
    const int b   = bid >> 4;             // batch (spread across XCDs)
    const int sub = bid & 15;             // column-slice owner
    const int j0  = sub * 16;
    const int q     = tid & 15;           // col within slice
    const int rbase = (tid >> 4) & 15;    // rows i = rbase+16m (compute threads)
    const int jcol  = j0 + q;
    const int wv = tid >> 6, ln = tid & 63;
    const bool cmp = (tid < 256);         // compute waves 0-3; wave 4 = DMA
    const int dl = tid & 63;              // DMA lane
    const int dro = dl >> 2, dco = 4 * (dl & 3);   // DMA row-offset/col-chunk

    __shared__ float s_actT[2][HH];       // act, transposed [(i&15)*16+(i>>4)]
    __shared__ float s_h[2][HH];
    __shared__ float s_red[4][16];
    __shared__ float s_o[4][2];
    __shared__ float s_x[2 * TT];
    __shared__ float s_wt[16][HH];        // w_hh rows j0..j0+15
    __shared__ float s_sn[2][HH][SNP];    // sn[t][b][row][j0+q], double-buffered

    u64* slotb = ws + (size_t)b * (2 * NSUB * 16);
    const int pt = *pt_ptr;

    // ---- prologue
    if (cmp) {
        for (int idx = tid; idx < 16 * HH; idx += 256)
            s_wt[idx >> 8][idx & 255] = w_hh[(size_t)(j0 + (idx >> 8)) * HH + (idx & 255)];
        const float hv = h0[b * HH + tid];
        s_h[0][tid] = hv;
        s_actT[0][(tid & 15) * 16 + (tid >> 4)] = tanhf(hv);
        if (tid < 2 * TT) s_x[tid] = x[b * 2 * TT + tid];
    } else {
        // DMA: stage sn[0] into buffer 0
        const float* snt = sn + (size_t)b * (HH * HH) + j0;
        #pragma unroll
        for (int k = 0; k < 16; ++k) {
            float4 v = *(const float4*)&snt[(size_t)(16 * k + dro) * HH + dco];
            *(float4*)&s_sn[0][16 * k + dro][dco] = v;
        }
    }

    float wi0 = 0.f, wi1 = 0.f, bh = 0.f, npv = 0.f, hreg = 0.f;
    if (tid < 16) {
        wi0  = w_in[jcol * 2 + 0];
        wi1  = w_in[jcol * 2 + 1];
        bh   = b_hh[jcol];
        npv  = nper[b * HH + jcol] * C_NOISE;
        hreg = h0[b * HH + jcol];
    }
    const float wo0 = cmp ? w_out[tid] : 0.f;
    const float wo1 = cmp ? w_out[HH + tid] : 0.f;
    __syncthreads();

    // M[m] = M[i][jcol], i = rbase+16m ; init = w_hh[jcol][i] (diff = 0)
    float M[16];
    if (cmp) {
        #pragma unroll
        for (int m = 0; m < 16; ++m) M[m] = s_wt[q][rbase + 16 * m];
    }

    for (int t = 0; t < TT; ++t) {
        const int cur = t & 1, nxt = cur ^ 1;
        const u32 tagw = (u32)(t + 1);

        float a[16];
        float4 vs[16];                    // DMA staging regs (dead on cmp path)
        if (cmp) {
            // ---- dot: act operands contiguous in s_actT -> 4 ds_read_b128
            #pragma unroll
            for (int mq = 0; mq < 4; ++mq) {
                float4 v = *(const float4*)&s_actT[cur][rbase * 16 + mq * 4];
                a[mq * 4 + 0] = v.x; a[mq * 4 + 1] = v.y;
                a[mq * 4 + 2] = v.z; a[mq * 4 + 3] = v.w;
            }
            float p = 0.f;
            #pragma unroll
            for (int m = 0; m < 16; ++m) p += a[m] * M[m];
            p += __shfl_xor(p, 16, 64);
            p += __shfl_xor(p, 32, 64);
            if (ln < 16) s_red[wv][ln] = p;
        } else if (t + 1 < TT) {
            // ---- DMA: issue sn[t+1] global loads (in flight across SYNC1)
            const float* snt = sn + ((size_t)(t + 1) * BB + b) * (HH * HH) + j0;
            #pragma unroll
            for (int k = 0; k < 16; ++k)
                vs[k] = *(const float4*)&snt[(size_t)(16 * k + dro) * HH + dco];
        }
        LGKM_BAR();                       // SYNC1 (no vmcnt drain)

        if (cmp) {
            // ---- owner: h update, publish IMMEDIATELY
            if (tid < 16) {
                const float dj = s_red[0][tid] + s_red[1][tid]
                               + s_red[2][tid] + s_red[3][tid];
                const float tmp = s_x[2 * t] * wi0 + s_x[2 * t + 1] * wi1 + bh + dj;
                hreg = 0.75f * hreg + 0.25f * tmp + ((t == pt) ? npv : 0.f);
                slot_put(slotb + (cur * NSUB + sub) * 16 + tid, pack(tagw, hreg));
                s_h[nxt][jcol] = hreg;
                s_actT[nxt][q * 16 + sub] = tanhf(hreg);
            }
            // ---- shadow: fold sn[t] from LDS + anti-Hebbian (register-only)
            {
                const float aj = s_actT[cur][q * 16 + sub];
                #pragma unroll
                for (int m = 0; m < 16; ++m)
                    M[m] += C_SN * s_sn[cur][rbase + 16 * m][q] - 0.1f * a[m] * aj;
            }
            // sub1 shadow: out[b][t-1] from s_h[cur]
            if (sub == 1) {
                const float hv = s_h[cur][tid];
                float p0 = hv * wo0, p1 = hv * wo1;
                #pragma unroll
                for (int off = 32; off; off >>= 1) {
                    p0 += __shfl_down(p0, off, 64);
                    p1 += __shfl_down(p1, off, 64);
                }
                if (ln == 0) { s_o[wv][0] = p0; s_o[wv][1] = p1; }
            }
            // ---- poll: ONE foreign slot per thread, throttled RMW spin.
            // Compute waves have NO outstanding vmem -> drain is clean.
            if (tid < 240) {
                int fs = tid >> 4; fs += (fs >= sub);
                const int fq = tid & 15;
                u64* sp = slotb + (cur * NSUB + fs) * 16 + fq;
                u64 v = slot_get(sp);
                while ((u32)(v >> 32) != tagw) {
                    __builtin_amdgcn_s_sleep(1);
                    v = slot_get(sp);
                }
                const float hr = __uint_as_float((u32)v);
                s_h[nxt][fs * 16 + fq] = hr;
                s_actT[nxt][fq * 16 + fs] = tanhf(hr);
            }
            // hid store post-poll (won't be drained until next step's poll)
            if (tid < 16) dout[((size_t)b * TT + t) * HH + jcol] = hreg;
        } else if (t + 1 < TT) {
            // ---- DMA: land sn[t+1] into the other buffer (compiler waits
            // vmcnt per-value; ds_writes drained by SYNC2's lgkmcnt)
            #pragma unroll
            for (int k = 0; k < 16; ++k)
                *(float4*)&s_sn[nxt][16 * k + dro][dco] = vs[k];
        }
        LGKM_BAR();                       // SYNC2

        if (sub == 1 && tid == 0 && t > 0) {
            dout[OUT_OFF + ((size_t)b * TT + (t - 1)) * 2 + 0] =
                s_o[0][0] + s_o[1][0] + s_o[2][0] + s_o[3][0];
            dout[OUT_OFF + ((size_t)b * TT + (t - 1)) * 2 + 1] =
                s_o[0][1] + s_o[1][1] + s_o[2][1] + s_o[3][1];
        }
    }

    // ---- epilogue: s_h[0] = h_64 (TT even)
    if (sub == 1) {
        float p0 = 0.f, p1 = 0.f;
        if (cmp) {
            const float hv = s_h[0][tid];
            p0 = hv * wo0; p1 = hv * wo1;
            #pragma unroll
            for (int off = 32; off; off >>= 1) {
                p0 += __shfl_down(p0, off, 64);
                p1 += __shfl_down(p1, off, 64);
            }
            if (ln == 0) { s_o[wv][0] = p0; s_o[wv][1] = p1; }
        }
        __syncthreads();                   // block-uniform branch: legal
        if (tid == 0) {
            dout[OUT_OFF + ((size_t)b * TT + (TT - 1)) * 2 + 0] =
                s_o[0][0] + s_o[1][0] + s_o[2][0] + s_o[3][0];
            dout[OUT_OFF + ((size_t)b * TT + (TT - 1)) * 2 + 1] =
                s_o[0][1] + s_o[1][1] + s_o[2][1] + s_o[3][1];
        }
    }
    if (sub == 2 && cmp) dout[HFIN_OFF + b * HH + tid] = s_h[0][tid];

    // new_j[b][i][jcol] = w_hh[i][jcol] + (M - w_hh[jcol][i])
    if (cmp) {
        #pragma unroll
        for (int m = 0; m < 16; ++m) {
            const int i = rbase + 16 * m;
            dout[NJ_OFF + ((size_t)b * HH + i) * HH + jcol] =
                w_hh[(size_t)i * HH + jcol] + M[m] - s_wt[q][i];
        }
    }
}

extern "C" void kernel_launch(void* const* d_in, const int* in_sizes, int n_in,
                              void* d_out, int out_size, void* d_ws, size_t ws_size,
                              hipStream_t stream) {
    (void)in_sizes; (void)n_in; (void)out_size; (void)ws_size;
    const float* x     = (const float*)d_in[0];
    const float* h0    = (const float*)d_in[1];
    const float* w_in  = (const float*)d_in[2];
    const float* w_hh  = (const float*)d_in[3];
    const float* b_hh  = (const float*)d_in[4];
    const float* w_out = (const float*)d_in[5];
    const float* nper  = (const float*)d_in[6];
    const float* sn    = (const float*)d_in[7];
    const int*   pt    = (const int*)d_in[8];
    float* dout        = (float*)d_out;
    u64* ws            = (u64*)d_ws;

    // zero the tagged slots each launch: tags in [1,64]; graph replays must
    // not see the previous launch's tags as valid.
    hipMemsetAsync(d_ws, 0, (size_t)BB * 2 * NSUB * 16 * sizeof(u64), stream);

    rnn_all<<<dim3(NBLK), dim3(NTH), 0, stream>>>(
        x, h0, w_in, w_hh, b_hh, w_out, nper, sn, pt, dout, ws);
}

// Round 18
// 135.545 us; speedup vs baseline: 1.3284x; 1.3284x over previous
//
#include <hip/hip_runtime.h>

// Problem constants
#define BB 16
#define TT 64
#define HH 256
#define NSUB 16              // blocks per batch; block owns a 16-COLUMN slice
#define NBLK (BB * NSUB)     // 256 blocks

// d_out layout (floats): hid[B][T][H], out[B][T][2], h_fin[B][H], new_j[B][H][H]
#define OUT_OFF  (BB * TT * HH)            // 262144
#define HFIN_OFF (OUT_OFF + BB * TT * 2)   // 264192
#define NJ_OFF   (HFIN_OFF + BB * HH)      // 268288

// beta * SIGMA_SYN * sqrt(beta) = 0.1 * 0.002 * sqrt(0.1)
#define C_SN    6.324555320336759e-05f
// PERT_SIGMA * sqrt(ALPHA) = 0.1 * 0.5
#define C_NOISE 0.05f

typedef unsigned long long u64;
typedef unsigned int u32;

// Agent-scope RMWs ONLY (proven r4-r17): exchange publishes at the device
// coherence point, fetch_add(0) reads fresh, tag travels with the data in
// one 8B packet -> no fences, no ordering assumptions.
// Refuted levers: relaxed loads (r2/r10), system-scope loads (r6), XCD-local
// atomics (r12/r13), padded lines (r15), per-wave publish (r16), DMA wave
// (r17), deeper poll pipelines (r9), LDS-only barriers (r14: neutral).
// r18: owners published AND polled -> in-order vmcnt made each owner-lane's
// first poll wait its own exchange ack (~1 RT); SYNC2 waits for the slowest
// poller, so this gated every step. Fix: publishers don't poll; the 16
// previously-idle threads (tid 240-255) take their poll targets.
__device__ __forceinline__ void slot_put(u64* p, u64 v) {
    (void)__hip_atomic_exchange(p, v, __ATOMIC_RELAXED, __HIP_MEMORY_SCOPE_AGENT);
}
__device__ __forceinline__ u64 slot_get(u64* p) {
    return __hip_atomic_fetch_add(p, 0ull, __ATOMIC_RELAXED, __HIP_MEMORY_SCOPE_AGENT);
}
__device__ __forceinline__ u64 pack(u32 tag, float v) {
    return ((u64)tag << 32) | (u64)__float_as_uint(v);
}

__global__ __launch_bounds__(256) void rnn_all(
    const float* __restrict__ x,      // [B,T,2]
    const float* __restrict__ h0,     // [B,H]
    const float* __restrict__ w_in,   // [H,2]
    const float* __restrict__ w_hh,   // [H,H]
    const float* __restrict__ b_hh,   // [H]
    const float* __restrict__ w_out,  // [2,H]
    const float* __restrict__ nper,   // [B,H]
    const float* __restrict__ sn,     // [T,B,H,H]
    const int*   __restrict__ pt_ptr, // scalar
    float*       __restrict__ dout,
    u64*         __restrict__ ws)     // d_ws: [BB][2][NSUB][16] u64 slots
{
    const int tid = threadIdx.x;
    const int bid = blockIdx.x;
    const int b   = bid >> 4;             // batch (spread across XCDs: r12 lesson)
    const int sub = bid & 15;             // column-slice owner
    const int j0  = sub * 16;
    const int q     = tid & 15;           // col within slice
    const int rbase = tid >> 4;           // this thread's rows: i = rbase+16m
    const int jcol  = j0 + q;             // this thread's M column (global)
    const int wv = tid >> 6, ln = tid & 63;

    // s_actT: TRANSPOSED act store: act[i] lives at [(i&15)*16 + (i>>4)]
    // -> thread (rbase,*) reads its 16 operands {rbase+16m} as 4 float4s.
    __shared__ float s_actT[2][HH];
    __shared__ float s_h[2][HH];          // raw h (for out / h_fin shadows)
    __shared__ float s_red[4][16];
    __shared__ float s_o[4][2];
    __shared__ float s_x[2 * TT];
    __shared__ float s_wt[16][HH];        // w_hh rows j0..j0+15

    u64* slotb = ws + (size_t)b * (2 * NSUB * 16);
    const int pt = *pt_ptr;

    // ---- prologue
    for (int idx = tid; idx < 16 * HH; idx += 256)
        s_wt[idx >> 8][idx & 255] = w_hh[(size_t)(j0 + (idx >> 8)) * HH + (idx & 255)];
    {
        const float hv = h0[b * HH + tid];
        s_h[0][tid] = hv;
        s_actT[0][(tid & 15) * 16 + (tid >> 4)] = tanhf(hv);
    }
    if (tid < 2 * TT) s_x[tid] = x[b * 2 * TT + tid];

    float wi0 = 0.f, wi1 = 0.f, bh = 0.f, npv = 0.f, hreg = 0.f;
    if (tid < 16) {
        wi0  = w_in[jcol * 2 + 0];
        wi1  = w_in[jcol * 2 + 1];
        bh   = b_hh[jcol];
        npv  = nper[b * HH + jcol] * C_NOISE;
        hreg = h0[b * HH + jcol];
    }
    const float wo0 = w_out[tid], wo1 = w_out[HH + tid];
    __syncthreads();

    // M[m] = M[i][jcol], i = rbase+16m ; init = w_hh[jcol][i] (diff = 0)
    float M[16];
    #pragma unroll
    for (int m = 0; m < 16; ++m) M[m] = s_wt[q][rbase + 16 * m];

    // sn prefetch t=0: sn[0][b][i][jcol]
    float sreg[16];
    {
        const float* snp = sn + ((size_t)b * HH + rbase) * HH + jcol;
        #pragma unroll
        for (int m = 0; m < 16; ++m) sreg[m] = snp[(size_t)(16 * m) * HH];
    }

    for (int t = 0; t < TT; ++t) {
        const int cur = t & 1, nxt = cur ^ 1;
        const u32 tagw = (u32)(t + 1);

        // ---- dot: act operands contiguous in s_actT -> 4 ds_read_b128
        float a[16];
        #pragma unroll
        for (int mq = 0; mq < 4; ++mq) {
            float4 v = *(const float4*)&s_actT[cur][rbase * 16 + mq * 4];
            a[mq * 4 + 0] = v.x; a[mq * 4 + 1] = v.y;
            a[mq * 4 + 2] = v.z; a[mq * 4 + 3] = v.w;
        }
        float p = 0.f;
        #pragma unroll
        for (int m = 0; m < 16; ++m) p += a[m] * M[m];
        p += __shfl_xor(p, 16, 64);       // combine rbase ^1
        p += __shfl_xor(p, 32, 64);       // combine rbase ^2
        if (ln < 16) s_red[wv][ln] = p;   // 4 wave-partials per column
        __syncthreads();                  // SYNC1

        // ---- owner: h update for own 16 columns, publish IMMEDIATELY.
        // Owners do NOT poll (r18): their exchange ack would serialize ahead
        // of any poll result-read in the in-order vmcnt queue.
        if (tid < 16) {
            const float dj = s_red[0][tid] + s_red[1][tid]
                           + s_red[2][tid] + s_red[3][tid];
            const float tmp = s_x[2 * t] * wi0 + s_x[2 * t + 1] * wi1 + bh + dj;
            hreg = 0.75f * hreg + 0.25f * tmp + ((t == pt) ? npv : 0.f);
            slot_put(slotb + (cur * NSUB + sub) * 16 + tid, pack(tagw, hreg));
            s_h[nxt][jcol] = hreg;
            s_actT[nxt][q * 16 + sub] = tanhf(hreg);
            dout[((size_t)b * TT + t) * HH + jcol] = hreg;   // hid
        }

        // ---- shadow: M step-t update (outer + sn[t]), prefetch sn[t+1]
        const float aj = s_actT[cur][q * 16 + sub];          // act[jcol]
        #pragma unroll
        for (int m = 0; m < 16; ++m)
            M[m] += C_SN * sreg[m] - 0.1f * a[m] * aj;
        if (t + 1 < TT) {
            const float* snp = sn + (((size_t)(t + 1) * BB + b) * HH + rbase) * HH + jcol;
            #pragma unroll
            for (int m = 0; m < 16; ++m) sreg[m] = snp[(size_t)(16 * m) * HH];
        }
        // sub1 shadow: out[b][t-1] = h_t @ w_out^T  (h_t = s_h[cur], stable)
        if (sub == 1) {
            const float hv = s_h[cur][tid];
            float p0 = hv * wo0, p1 = hv * wo1;
            #pragma unroll
            for (int off = 32; off; off >>= 1) {
                p0 += __shfl_down(p0, off, 64);
                p1 += __shfl_down(p1, off, 64);
            }
            if (ln == 0) { s_o[wv][0] = p0; s_o[wv][1] = p1; }
        }

        // ---- poll: tid in [16,256) -> 240 pollers, one foreign slot each,
        // throttled single-RMW spin (r11). Publishers excluded.
        if (tid >= 16) {
            const int idx = tid - 16;                        // 0..239
            int fs = idx >> 4; fs += (fs >= sub);            // foreign sub id
            const int fq = idx & 15;
            u64* sp = slotb + (cur * NSUB + fs) * 16 + fq;
            u64 v = slot_get(sp);
            while ((u32)(v >> 32) != tagw) {
                __builtin_amdgcn_s_sleep(1);
                v = slot_get(sp);
            }
            const float hr = __uint_as_float((u32)v);
            s_h[nxt][fs * 16 + fq] = hr;
            s_actT[nxt][fq * 16 + fs] = tanhf(hr);           // fused tanh
        }
        __syncthreads();                  // SYNC2: s_h/s_actT[nxt] complete

        if (sub == 1 && tid == 0 && t > 0) {
            dout[OUT_OFF + ((size_t)b * TT + (t - 1)) * 2 + 0] =
                s_o[0][0] + s_o[1][0] + s_o[2][0] + s_o[3][0];
            dout[OUT_OFF + ((size_t)b * TT + (t - 1)) * 2 + 1] =
                s_o[0][1] + s_o[1][1] + s_o[2][1] + s_o[3][1];
        }
    }

    // ---- epilogue: s_h[0] = h_64 (TT even)
    if (sub == 1) {
        const float hv = s_h[0][tid];
        float p0 = hv * wo0, p1 = hv * wo1;
        #pragma unroll
        for (int off = 32; off; off >>= 1) {
            p0 += __shfl_down(p0, off, 64);
            p1 += __shfl_down(p1, off, 64);
        }
        if (ln == 0) { s_o[wv][0] = p0; s_o[wv][1] = p1; }
        __syncthreads();                   // block-uniform branch: legal
        if (tid == 0) {
            dout[OUT_OFF + ((size_t)b * TT + (TT - 1)) * 2 + 0] =
                s_o[0][0] + s_o[1][0] + s_o[2][0] + s_o[3][0];
            dout[OUT_OFF + ((size_t)b * TT + (TT - 1)) * 2 + 1] =
                s_o[0][1] + s_o[1][1] + s_o[2][1] + s_o[3][1];
        }
    }
    if (sub == 2) dout[HFIN_OFF + b * HH + tid] = s_h[0][tid];

    // new_j[b][i][jcol] = w_hh[i][jcol] + (M - w_hh[jcol][i])
    #pragma unroll
    for (int m = 0; m < 16; ++m) {
        const int i = rbase + 16 * m;
        dout[NJ_OFF + ((size_t)b * HH + i) * HH + jcol] =
            w_hh[(size_t)i * HH + jcol] + M[m] - s_wt[q][i];
    }
}

extern "C" void kernel_launch(void* const* d_in, const int* in_sizes, int n_in,
                              void* d_out, int out_size, void* d_ws, size_t ws_size,
                              hipStream_t stream) {
    (void)in_sizes; (void)n_in; (void)out_size; (void)ws_size;
    const float* x     = (const float*)d_in[0];
    const float* h0    = (const float*)d_in[1];
    const float* w_in  = (const float*)d_in[2];
    const float* w_hh  = (const float*)d_in[3];
    const float* b_hh  = (const float*)d_in[4];
    const float* w_out = (const float*)d_in[5];
    const float* nper  = (const float*)d_in[6];
    const float* sn    = (const float*)d_in[7];
    const int*   pt    = (const int*)d_in[8];
    float* dout        = (float*)d_out;
    u64* ws            = (u64*)d_ws;

    // zero the tagged slots each launch: tags in [1,64]; a replayed graph
    // must not see the previous launch's tags as valid.
    hipMemsetAsync(d_ws, 0, (size_t)BB * 2 * NSUB * 16 * sizeof(u64), stream);

    rnn_all<<<dim3(NBLK), dim3(256), 0, stream>>>(
        x, h0, w_in, w_hh, b_hh, w_out, nper, sn, pt, dout, ws);
}